// Round 4
// baseline (547.997 us; speedup 1.0000x reference)
//
#include <hip/hip_runtime.h>
#include <hip/hip_bf16.h>

typedef unsigned short u16;
typedef unsigned int u32;
typedef unsigned long long u64;
typedef __attribute__((ext_vector_type(8))) short short8;
typedef __attribute__((ext_vector_type(4))) float floatx4;

#define AS1 __attribute__((address_space(1)))
#define AS3 __attribute__((address_space(3)))

// ---- bf16 <-> f32 helpers (raw bits, RNE) ----
__device__ __forceinline__ float bf2f(u16 u) {
    u32 x = ((u32)u) << 16;
    float f;
    __builtin_memcpy(&f, &x, 4);
    return f;
}
__device__ __forceinline__ u16 f2bf(float f) {
    u32 x;
    __builtin_memcpy(&x, &f, 4);
    u32 r = (x + 0x7fffu + ((x >> 16) & 1u)) >> 16;
    return (u16)r;
}
// packed 2xf32 -> 2xbf16 (v_cvt_pk_bf16_f32), returned as u32 (lo=first)
__device__ __forceinline__ u32 f2bf_pk(float a, float b) {
    __hip_bfloat162 h = __float22bfloat162_rn(float2{a, b});
    u32 r;
    __builtin_memcpy(&r, &h, 4);
    return r;
}

// ==========================================================================
// Merged prep: z<4 = weight transposes (f32 RxC -> bf16 CxR), z=4 = X cast.
// ==========================================================================
__global__ __launch_bounds__(1024) void prep_weights(const float* __restrict__ Wq,
                                                     const float* __restrict__ Wk,
                                                     const float* __restrict__ Wv,
                                                     const float* __restrict__ Wo,
                                                     const float* __restrict__ X,
                                                     u16* __restrict__ WqkvT,
                                                     u16* __restrict__ WoT,
                                                     u16* __restrict__ Xb) {
    const int z = blockIdx.z;
    const int tx = threadIdx.x, ty = threadIdx.y;
    if (z == 4) {  // convert X: 2048 active blocks x 4096 floats
        int idx = blockIdx.y * 64 + blockIdx.x;
        if (idx >= 2048) return;
        int tid = ty * 32 + tx;
        size_t i = (size_t)idx * 4096 + (size_t)tid * 4;
        float4 v = *(const float4*)(X + i);
        u16 o[4] = {f2bf(v.x), f2bf(v.y), f2bf(v.z), f2bf(v.w)};
        *(u64*)(Xb + i) = *(u64*)o;
        return;
    }
    const float* in;
    u16* out;
    int C;
    if (z == 0) { in = Wq; out = WqkvT; C = 2048; }
    else if (z == 1) { in = Wk; out = WqkvT + 2048 * 2048; C = 1024; }
    else if (z == 2) { in = Wv; out = WqkvT + 3072 * 2048; C = 1024; }
    else { in = Wo; out = WoT; C = 2048; }
    const int c0 = blockIdx.x * 32, r0 = blockIdx.y * 32;
    if (c0 >= C) return;
    __shared__ u16 t[32][33];
    t[ty][tx] = f2bf(in[(size_t)(r0 + ty) * C + c0 + tx]);
    __syncthreads();
    out[(size_t)(c0 + ty) * 2048 + r0 + tx] = t[tx][ty];
}

// ==========================================================================
// GEMM: C[M,N] = A[M,K] @ Bt[N,K]^T (bf16 in, fp32 acc, OUT_T out)
// 256x256 tile, BK=64, 512 thr (8 waves 2Mx4N), 8-phase-per-2-K-tiles
// schedule: counted vmcnt(6), raw s_barrier, XOR-swizzled LDS, setprio.
// ==========================================================================
template <typename OUT_T>
__global__ __launch_bounds__(512, 2) void gemm256(const u16* __restrict__ A,
                                                  const u16* __restrict__ Bt,
                                                  OUT_T* __restrict__ C,
                                                  int M, int N, int K) {
    (void)M;
    __shared__ __align__(16) u16 lds[2][2][2][128 * 64];  // [buf][A/B][half][r*64+c]
    const int tid = threadIdx.x;
    const int wave = tid >> 6, lane = tid & 63;
    const int lr = lane & 15, lq = lane >> 4;
    const int wm = wave >> 2, wn = wave & 3;
    const int m0 = blockIdx.y * 256, n0 = blockIdx.x * 256;

    const int srow = lane >> 3;                    // 0..7 within 8-row group
    const int schunk = ((lane & 7) ^ srow) << 3;   // source chunk (elems)
    const int slot = wave << 1;

    auto stage = [&](const u16* src, int rbase, int buf, int mat, int half, int k0) {
#pragma unroll
        for (int j = 0; j < 2; j++) {
            int r = rbase + half * 128 + (slot + j) * 8 + srow;
            __builtin_amdgcn_global_load_lds(
                (const AS1 void*)(src + (size_t)r * K + k0 + schunk),
                (AS3 void*)(&lds[buf][mat][half][(slot + j) * 512]), 16, 0, 0);
        }
    };

    floatx4 zf = {0.f, 0.f, 0.f, 0.f};
    floatx4 acc[8][4];
#pragma unroll
    for (int i = 0; i < 8; i++)
#pragma unroll
        for (int jn = 0; jn < 4; jn++) acc[i][jn] = zf;

    const int NT = K >> 6;

    stage(Bt, n0, 0, 1, 0, 0);
    stage(Bt, n0, 0, 1, 1, 0);
    stage(A, m0, 0, 0, 0, 0);
    stage(A, m0, 0, 0, 1, 0);
    if (NT > 1) {
        stage(Bt, n0, 1, 1, 0, 64);
        stage(Bt, n0, 1, 1, 1, 64);
        stage(A, m0, 1, 0, 0, 64);
        asm volatile("s_waitcnt vmcnt(6)" ::: "memory");
    } else {
        asm volatile("s_waitcnt vmcnt(0)" ::: "memory");
    }
    __builtin_amdgcn_s_barrier();

    for (int kt = 0; kt < NT; kt++) {
        const int b = kt & 1;
        const u16* Ab = &lds[b][0][wm][0];
        const u16* Bb = &lds[b][1][wn >> 1][0];
        const int brow = (wn & 1) * 64;
        const int sx = lr & 7;
        const int nk = (kt + 2) << 6;

        // ---- phase 0 ----
        short8 bf0[4], bf1[4], af[4];
#pragma unroll
        for (int jn = 0; jn < 4; jn++) {
            int rh = brow + jn * 16 + lr;
            bf0[jn] = *(const short8*)(Bb + rh * 64 + ((lq ^ sx) << 3));
            bf1[jn] = *(const short8*)(Bb + rh * 64 + (((4 + lq) ^ sx) << 3));
        }
#pragma unroll
        for (int i = 0; i < 4; i++)
            af[i] = *(const short8*)(Ab + (i * 16 + lr) * 64 + ((lq ^ sx) << 3));
        if (kt + 1 < NT) stage(A, m0, b ^ 1, 0, 1, (kt + 1) << 6);
        __builtin_amdgcn_s_barrier();
        asm volatile("s_waitcnt lgkmcnt(0)" ::: "memory");
        __builtin_amdgcn_sched_barrier(0);
        __builtin_amdgcn_s_setprio(1);
#pragma unroll
        for (int i = 0; i < 4; i++)
#pragma unroll
            for (int jn = 0; jn < 4; jn++)
                acc[i][jn] = __builtin_amdgcn_mfma_f32_16x16x32_bf16(af[i], bf0[jn], acc[i][jn], 0, 0, 0);
        __builtin_amdgcn_s_setprio(0);
        __builtin_amdgcn_s_barrier();

        // ---- phase 1 ----
        short8 ag[4];
#pragma unroll
        for (int i = 0; i < 4; i++)
            ag[i] = *(const short8*)(Ab + ((i + 4) * 16 + lr) * 64 + ((lq ^ sx) << 3));
        if (kt + 2 < NT) stage(Bt, n0, b, 1, 0, nk);
        __builtin_amdgcn_s_barrier();
        asm volatile("s_waitcnt lgkmcnt(0)" ::: "memory");
        __builtin_amdgcn_sched_barrier(0);
        __builtin_amdgcn_s_setprio(1);
#pragma unroll
        for (int i = 0; i < 4; i++)
#pragma unroll
            for (int jn = 0; jn < 4; jn++)
                acc[i + 4][jn] = __builtin_amdgcn_mfma_f32_16x16x32_bf16(ag[i], bf0[jn], acc[i + 4][jn], 0, 0, 0);
        __builtin_amdgcn_s_setprio(0);
        __builtin_amdgcn_s_barrier();

        // ---- phase 2 ----
        short8 c0[4], c1[4];
#pragma unroll
        for (int i = 0; i < 4; i++) {
            c0[i] = *(const short8*)(Ab + (i * 16 + lr) * 64 + (((4 + lq) ^ sx) << 3));
            c1[i] = *(const short8*)(Ab + ((i + 4) * 16 + lr) * 64 + (((4 + lq) ^ sx) << 3));
        }
        if (kt + 2 < NT) stage(Bt, n0, b, 1, 1, nk);
        __builtin_amdgcn_s_barrier();
        asm volatile("s_waitcnt lgkmcnt(0)" ::: "memory");
        __builtin_amdgcn_sched_barrier(0);
        __builtin_amdgcn_s_setprio(1);
#pragma unroll
        for (int i = 0; i < 4; i++)
#pragma unroll
            for (int jn = 0; jn < 4; jn++)
                acc[i][jn] = __builtin_amdgcn_mfma_f32_16x16x32_bf16(c0[i], bf1[jn], acc[i][jn], 0, 0, 0);
        __builtin_amdgcn_s_setprio(0);
        __builtin_amdgcn_s_barrier();

        // ---- phase 3 ----
        if (kt + 2 < NT) stage(A, m0, b, 0, 0, nk);
        __builtin_amdgcn_s_barrier();
        __builtin_amdgcn_s_setprio(1);
#pragma unroll
        for (int i = 0; i < 4; i++)
#pragma unroll
            for (int jn = 0; jn < 4; jn++)
                acc[i + 4][jn] = __builtin_amdgcn_mfma_f32_16x16x32_bf16(c1[i], bf1[jn], acc[i + 4][jn], 0, 0, 0);
        __builtin_amdgcn_s_setprio(0);
        if (kt + 2 < NT) asm volatile("s_waitcnt vmcnt(6)" ::: "memory");
        else asm volatile("s_waitcnt vmcnt(0)" ::: "memory");
        __builtin_amdgcn_s_barrier();
    }

#pragma unroll
    for (int i = 0; i < 8; i++)
#pragma unroll
        for (int jn = 0; jn < 4; jn++)
#pragma unroll
            for (int r = 0; r < 4; r++) {
                int row = m0 + wm * 128 + i * 16 + lq * 4 + r;
                int col = n0 + wn * 64 + jn * 16 + lr;
                if constexpr (sizeof(OUT_T) == 2)
                    C[(size_t)row * N + col] = f2bf(acc[i][jn][r]);
                else
                    C[(size_t)row * N + col] = acc[i][jn][r];
            }
}

// ==========================================================================
// GEMM: BM=256 x BN=128, BK=64, 512 thr = 8 waves (4M x 2N), 64x64/wave.
// Same 8-phase counted-vmcnt schedule; 3 stage-units/tile -> vmcnt(4).
// Grid (N/128, M/256) -> 256 blocks for the Wo GEMM (full GPU).
// ==========================================================================
template <typename OUT_T>
__global__ __launch_bounds__(512, 2) void gemm128n(const u16* __restrict__ A,
                                                   const u16* __restrict__ Bt,
                                                   OUT_T* __restrict__ C,
                                                   int M, int N, int K) {
    (void)M;
    __shared__ __align__(16) u16 Abuf[2][2][128 * 64];  // [buf][half][r*64+c]
    __shared__ __align__(16) u16 Bbuf[2][128 * 64];     // [buf][r*64+c]
    const int tid = threadIdx.x;
    const int wave = tid >> 6, lane = tid & 63;
    const int lr = lane & 15, lq = lane >> 4;
    const int wm = wave >> 1, wn = wave & 1;
    const int m0 = blockIdx.y * 256, n0 = blockIdx.x * 128;

    const int srow = lane >> 3;
    const int schunk = ((lane & 7) ^ srow) << 3;
    const int slot = wave << 1;

    auto stage = [&](const u16* src, int rowbase, u16* ldsbase, int k0) {
#pragma unroll
        for (int j = 0; j < 2; j++) {
            int r = rowbase + (slot + j) * 8 + srow;
            __builtin_amdgcn_global_load_lds(
                (const AS1 void*)(src + (size_t)r * K + k0 + schunk),
                (AS3 void*)(ldsbase + (slot + j) * 512), 16, 0, 0);
        }
    };

    floatx4 zf = {0.f, 0.f, 0.f, 0.f};
    floatx4 acc[4][4];
#pragma unroll
    for (int i = 0; i < 4; i++)
#pragma unroll
        for (int jn = 0; jn < 4; jn++) acc[i][jn] = zf;

    const int NT = K >> 6;

    // prologue: t0 = {Ah0, Ah1, B}; t1 = {Ah0, B} (Ah1(t1) comes in t0.ph0)
    stage(A, m0, &Abuf[0][0][0], 0);
    stage(A, m0 + 128, &Abuf[0][1][0], 0);
    stage(Bt, n0, &Bbuf[0][0], 0);
    if (NT > 1) {
        stage(A, m0, &Abuf[1][0][0], 64);
        stage(Bt, n0, &Bbuf[1][0], 64);
        asm volatile("s_waitcnt vmcnt(4)" ::: "memory");
    } else {
        asm volatile("s_waitcnt vmcnt(0)" ::: "memory");
    }
    __builtin_amdgcn_s_barrier();

    for (int kt = 0; kt < NT; kt++) {
        const int b = kt & 1;
        const u16* Ab = &Abuf[b][wm >> 1][0];
        const u16* Bb = &Bbuf[b][0];
        const int ar = (wm & 1) * 64;
        const int br = wn * 64;
        const int sx = lr & 7;
        const int nk = (kt + 2) << 6;

        // ---- phase 0: read bf0,bf1,af(kk0); stage Ah1(kt+1); mfma kk0 i0-1 ----
        short8 bf0[4], bf1[4], af[4];
#pragma unroll
        for (int jn = 0; jn < 4; jn++) {
            int rh = br + jn * 16 + lr;
            bf0[jn] = *(const short8*)(Bb + rh * 64 + ((lq ^ sx) << 3));
            bf1[jn] = *(const short8*)(Bb + rh * 64 + (((4 + lq) ^ sx) << 3));
        }
#pragma unroll
        for (int i = 0; i < 4; i++)
            af[i] = *(const short8*)(Ab + (ar + i * 16 + lr) * 64 + ((lq ^ sx) << 3));
        if (kt + 1 < NT) stage(A, m0 + 128, &Abuf[b ^ 1][1][0], (kt + 1) << 6);
        __builtin_amdgcn_s_barrier();
        asm volatile("s_waitcnt lgkmcnt(0)" ::: "memory");
        __builtin_amdgcn_sched_barrier(0);
        __builtin_amdgcn_s_setprio(1);
#pragma unroll
        for (int i = 0; i < 2; i++)
#pragma unroll
            for (int jn = 0; jn < 4; jn++)
                acc[i][jn] = __builtin_amdgcn_mfma_f32_16x16x32_bf16(af[i], bf0[jn], acc[i][jn], 0, 0, 0);
        __builtin_amdgcn_s_setprio(0);
        __builtin_amdgcn_s_barrier();

        // ---- phase 1: stage B(kt+2); mfma kk0 i2-3 ----
        if (kt + 2 < NT) stage(Bt, n0, &Bbuf[b][0], nk);
        __builtin_amdgcn_s_barrier();
        __builtin_amdgcn_s_setprio(1);
#pragma unroll
        for (int i = 2; i < 4; i++)
#pragma unroll
            for (int jn = 0; jn < 4; jn++)
                acc[i][jn] = __builtin_amdgcn_mfma_f32_16x16x32_bf16(af[i], bf0[jn], acc[i][jn], 0, 0, 0);
        __builtin_amdgcn_s_setprio(0);
        __builtin_amdgcn_s_barrier();

        // ---- phase 2: read ag(kk1); mfma kk1 i0-1 ----
        short8 ag[4];
#pragma unroll
        for (int i = 0; i < 4; i++)
            ag[i] = *(const short8*)(Ab + (ar + i * 16 + lr) * 64 + (((4 + lq) ^ sx) << 3));
        __builtin_amdgcn_s_barrier();
        asm volatile("s_waitcnt lgkmcnt(0)" ::: "memory");
        __builtin_amdgcn_sched_barrier(0);
        __builtin_amdgcn_s_setprio(1);
#pragma unroll
        for (int i = 0; i < 2; i++)
#pragma unroll
            for (int jn = 0; jn < 4; jn++)
                acc[i][jn] = __builtin_amdgcn_mfma_f32_16x16x32_bf16(ag[i], bf1[jn], acc[i][jn], 0, 0, 0);
        __builtin_amdgcn_s_setprio(0);
        __builtin_amdgcn_s_barrier();

        // ---- phase 3: stage Ah0(kt+2); mfma kk1 i2-3; counted vmcnt ----
        if (kt + 2 < NT) stage(A, m0, &Abuf[b][0][0], nk);
        __builtin_amdgcn_s_barrier();
        __builtin_amdgcn_s_setprio(1);
#pragma unroll
        for (int i = 2; i < 4; i++)
#pragma unroll
            for (int jn = 0; jn < 4; jn++)
                acc[i][jn] = __builtin_amdgcn_mfma_f32_16x16x32_bf16(ag[i], bf1[jn], acc[i][jn], 0, 0, 0);
        __builtin_amdgcn_s_setprio(0);
        if (kt + 2 < NT) asm volatile("s_waitcnt vmcnt(4)" ::: "memory");
        else asm volatile("s_waitcnt vmcnt(0)" ::: "memory");
        __builtin_amdgcn_s_barrier();
    }

#pragma unroll
    for (int i = 0; i < 4; i++)
#pragma unroll
        for (int jn = 0; jn < 4; jn++)
#pragma unroll
            for (int r = 0; r < 4; r++) {
                int row = m0 + wm * 64 + i * 16 + lq * 4 + r;
                int col = n0 + wn * 64 + jn * 16 + lr;
                if constexpr (sizeof(OUT_T) == 2)
                    C[(size_t)row * N + col] = f2bf(acc[i][jn][r]);
                else
                    C[(size_t)row * N + col] = acc[i][jn][r];
            }
}

// ==========================================================================
// Merged post-QKV prep: blocks <24576 do RMS-norm+RoPE on Q/K (in place);
// blocks >=24576 transpose V into Vt (b,kv,d,s). 256 threads each.
// ==========================================================================
__global__ __launch_bounds__(256) void prep_qkv(u16* __restrict__ QKV,
                                                u16* __restrict__ Vt,
                                                const float* __restrict__ cosb,
                                                const float* __restrict__ sinb,
                                                const float* __restrict__ qw,
                                                const float* __restrict__ kw) {
    const int bx = blockIdx.x;
    const int tid = threadIdx.x;
    if (bx >= 24576) {  // V transpose: 4096 blocks
        const int idx = bx - 24576;
        const int s0 = (idx & 63) * 32;
        const int d0 = ((idx >> 6) & 3) * 32;
        const int zz = idx >> 8;
        const int b = zz >> 3, kv = zz & 7;
        __shared__ u16 t[32][33];
        const int tx = tid & 31, ty0 = tid >> 5;  // 32 x 8
#pragma unroll
        for (int p = 0; p < 4; p++) {
            int r = ty0 + p * 8;
            t[r][tx] = QKV[(size_t)(b * 2048 + s0 + r) * 4096 + 3072 + kv * 128 + d0 + tx];
        }
        __syncthreads();
#pragma unroll
        for (int p = 0; p < 4; p++) {
            int r = ty0 + p * 8;
            Vt[(size_t)((b * 8 + kv) * 128 + d0 + r) * 2048 + s0 + tx] = t[tx][r];
        }
        return;
    }
    const int wave = tid >> 6, lane = tid & 63;
    const int t = bx * 4 + wave;  // 0..98303
    u16* ptr;
    const float* w;
    float scale;
    int bs;
    if (t < 65536) {
        bs = t >> 4;
        ptr = QKV + (size_t)bs * 4096 + (t & 15) * 128;
        w = qw;
        scale = 0.08838834764831845f * 1.4426950408889634f;  // D^-0.5 * log2(e)
    } else {
        int t2 = t - 65536;
        bs = t2 >> 3;
        ptr = QKV + (size_t)bs * 4096 + 2048 + (t2 & 7) * 128;
        w = kw;
        scale = 1.0f;
    }
    const int d = lane * 2;
    u32 xv = *(const u32*)(ptr + d);
    float x0 = bf2f((u16)(xv & 0xffff)), x1 = bf2f((u16)(xv >> 16));
    float ss = x0 * x0 + x1 * x1;
#pragma unroll
    for (int off = 1; off < 64; off <<= 1) ss += __shfl_xor(ss, off);
    float rn = rsqrtf(ss * (1.0f / 128.0f) + 1e-6f);
    float2 wv = *(const float2*)(w + d);
    float y0 = x0 * rn * wv.x;
    float y1 = x1 * rn * wv.y;
    float p0 = __shfl_xor(y0, 32);
    float p1 = __shfl_xor(y1, 32);
    float sgn = (lane < 32) ? -1.0f : 1.0f;
    float2 cv = *(const float2*)(cosb + (size_t)bs * 128 + d);
    float2 sv = *(const float2*)(sinb + (size_t)bs * 128 + d);
    float o0 = (y0 * cv.x + sgn * p0 * sv.x) * scale;
    float o1 = (y1 * cv.y + sgn * p1 * sv.y) * scale;
    *(u32*)(ptr + d) = (u32)f2bf(o0) | ((u32)f2bf(o1) << 16);
}

// ==========================================================================
// Causal GQA flash attention, transposed-score formulation.
// QBLK=64 (4 waves, 256 thr), KVBLK=64. K double-buffered in 32KB LDS;
// V read directly from global Vt (L2-resident; swizzle pair cancels ->
// plain chunk index). 4 blocks/CU = 16 waves/CU sustained.
// Flat 1024-block grid with per-CU work balancing: assuming round-robin
// placement (CU ~ id mod 256), CU c hosts qt = {xx, 31-xx, xx, 31-xx}
// -> exactly 66 key-tiles per CU (perf heuristic only, not correctness).
// T5 setprio, T13 defer-max, per-lane partial l.
// ==========================================================================
__global__ __launch_bounds__(256, 4) void attn_kernel(const u16* __restrict__ QKV,
                                                      const u16* __restrict__ Vt,
                                                      u16* __restrict__ O) {
    __shared__ __align__(16) u16 Ks[2][64 * 128];   // [key][d] swizzled, 32KB
    const int tid = threadIdx.x;
    const int wave = tid >> 6, lane = tid & 63;
    const int lr = lane & 15, lq = lane >> 4;

    // balanced flat decode
    const int id = blockIdx.x;       // 0..1023
    const int g = id >> 8;           // 0..3
    const int c = id & 255;
    const int xx = c & 31;
    const int hh = c >> 5;           // 0..7
    const int qt = (g & 1) ? (31 - xx) : xx;
    const int h = hh + ((g & 2) << 2);
    const int b = g & 1;

    const int kv = h >> 1;
    const int q0 = qt * 64;
    const int wq = wave * 16;

    // async stage of one 64-key K tile into buffer `buf` (4 instrs/wave)
    auto stageK = [&](int buf, int k0s) {
#pragma unroll
        for (int j = 0; j < 4; j++) {   // Ks: 64 rows x 256 B
            int r = wave * 16 + j * 4 + (lane >> 4);
            int ch = (lane & 15) ^ (r & 15);   // inverse-swizzled source chunk
            __builtin_amdgcn_global_load_lds(
                (const AS1 void*)(QKV + (size_t)(b * 2048 + k0s + r) * 4096 + 2048 + kv * 128 + ch * 8),
                (AS3 void*)(&Ks[buf][(wave * 16 + j * 4) * 128]), 16, 0, 0);
        }
    };

    // Q fragments in registers (B-operand: n=qrow on lr, k=d on lq*8+j)
    short8 qf[4];
#pragma unroll
    for (int t = 0; t < 4; t++)
        qf[t] = *(const short8*)(QKV + (size_t)(b * 2048 + q0 + wq + lr) * 4096 + h * 128 + t * 32 + lq * 8);

    // V global base: row = (b*8+kv)*128 + jn*16 + lr, elems at k0 + chunk*8 + (lq&1)*4
    const u16* vbase0 = Vt + ((size_t)((b * 8 + kv) * 128) + lr) * 2048 + (lq & 1) * 4;

    floatx4 zf = {0.f, 0.f, 0.f, 0.f};
    floatx4 oacc[8];
#pragma unroll
    for (int jn = 0; jn < 8; jn++) oacc[jn] = zf;
    float mstate = -1e30f;
    float lstate = 0.f;   // per-lane partial; cross-quad reduce in epilogue

    const int nIter = qt + 1;

    stageK(0, 0);

    for (int kt = 0; kt < nIter; kt++) {
        const int k0 = kt * 64;
        const int cur = kt & 1;
        __syncthreads();   // drain: K(kt) committed; all waves done with buf cur^1
        if (kt + 1 < nIter) stageK(cur ^ 1, k0 + 64);

        // wave-level causal skip
        if (k0 <= q0 + wq + 15) {
            const u16* KsC = &Ks[cur][0];
            floatx4 sacc[4];
#pragma unroll
            for (int jm = 0; jm < 4; jm++) sacc[jm] = zf;
            __builtin_amdgcn_s_setprio(1);
#pragma unroll
            for (int t = 0; t < 4; t++) {
                short8 a[4];
#pragma unroll
                for (int jm = 0; jm < 4; jm++)
                    a[jm] = *(const short8*)(KsC + (jm * 16 + lr) * 128 + (((t * 4 + lq) ^ lr) << 3));
#pragma unroll
                for (int jm = 0; jm < 4; jm++)
                    sacc[jm] = __builtin_amdgcn_mfma_f32_16x16x32_bf16(a[jm], qf[t], sacc[jm], 0, 0, 0);
            }
            __builtin_amdgcn_s_setprio(0);

            if (k0 + 63 > q0 + wq) {
#pragma unroll
                for (int jm = 0; jm < 4; jm++) {
                    int diff = (q0 + wq + lr) - (k0 + jm * 16 + lq * 4);
#pragma unroll
                    for (int r = 0; r < 4; r++)
                        if (r > diff) sacc[jm][r] = -1e30f;
                }
            }

            // per-qrow max (tree within jm, then cross-quad)
            float mx = -1e30f;
#pragma unroll
            for (int jm = 0; jm < 4; jm++) {
                float a0 = fmaxf(sacc[jm][0], sacc[jm][1]);
                float a1 = fmaxf(sacc[jm][2], sacc[jm][3]);
                mx = fmaxf(mx, fmaxf(a0, a1));
            }
            mx = fmaxf(mx, __shfl_xor(mx, 16));
            mx = fmaxf(mx, __shfl_xor(mx, 32));

            // T13 defer-max: skip rescale when all rows grew <= 8 (log2 dom)
            bool defer = __all(mx - mstate <= 8.0f);
            float mnew = defer ? mstate : fmaxf(mstate, mx);

            float rs = 0.f;
#pragma unroll
            for (int jm = 0; jm < 4; jm++)
#pragma unroll
                for (int r = 0; r < 4; r++) {
                    float p = exp2f(sacc[jm][r] - mnew);
                    sacc[jm][r] = p;
                    rs += p;
                }

            if (!defer) {
                float alpha = exp2f(mstate - mnew);
                mstate = mnew;
                lstate *= alpha;
                float ao[4];
#pragma unroll
                for (int r = 0; r < 4; r++) ao[r] = __shfl(alpha, lq * 4 + r);
#pragma unroll
                for (int jn = 0; jn < 8; jn++)
#pragma unroll
                    for (int r = 0; r < 4; r++) oacc[jn][r] *= ao[r];
            }
            lstate += rs;

            u64 pb[4];
#pragma unroll
            for (int jm = 0; jm < 4; jm++) {
                u32 lo = f2bf_pk(sacc[jm][0], sacc[jm][1]);
                u32 hi = f2bf_pk(sacc[jm][2], sacc[jm][3]);
                pb[jm] = (u64)lo | ((u64)hi << 32);
            }

            // O += P @ V; V fragments straight from global Vt (L2-hot).
            const u16* vb0 = vbase0 + k0;
            __builtin_amdgcn_s_setprio(1);
#pragma unroll
            for (int t = 0; t < 2; t++) {
                union { short8 v; u64 q[2]; } pa;
                pa.q[0] = pb[2 * t];
                pa.q[1] = pb[2 * t + 1];
#pragma unroll
                for (int jn = 0; jn < 8; jn++) {
                    const u16* vrow = vb0 + (size_t)(jn * 16) * 2048;
                    union { short8 v; u64 q[2]; } vb;
                    vb.q[0] = *(const u64*)(vrow + (t * 4 + (lq >> 1)) * 8);
                    vb.q[1] = *(const u64*)(vrow + (t * 4 + 2 + (lq >> 1)) * 8);
                    oacc[jn] = __builtin_amdgcn_mfma_f32_16x16x32_bf16(pa.v, vb.v, oacc[jn], 0, 0, 0);
                }
            }
            __builtin_amdgcn_s_setprio(0);
        }
    }

    // epilogue: finish l reduce, then O / l
    lstate += __shfl_xor(lstate, 16);
    lstate += __shfl_xor(lstate, 32);
    float lo[4];
#pragma unroll
    for (int r = 0; r < 4; r++) lo[r] = __shfl(lstate, lq * 4 + r);
#pragma unroll
    for (int jn = 0; jn < 8; jn++)
#pragma unroll
        for (int r = 0; r < 4; r++) {
            int row = q0 + wq + lq * 4 + r;
            O[(size_t)(b * 2048 + row) * 2048 + h * 128 + jn * 16 + lr] =
                f2bf(oacc[jn][r] / lo[r]);
        }
}

// ==========================================================================
extern "C" void kernel_launch(void* const* d_in, const int* in_sizes, int n_in,
                              void* d_out, int out_size, void* d_ws, size_t ws_size,
                              hipStream_t stream) {
    const float* X = (const float*)d_in[0];
    const float* cosb = (const float*)d_in[1];
    const float* sinb = (const float*)d_in[2];
    const float* Wq = (const float*)d_in[3];
    const float* Wk = (const float*)d_in[4];
    const float* Wv = (const float*)d_in[5];
    const float* Wo = (const float*)d_in[6];
    const float* qw = (const float*)d_in[7];
    const float* kw = (const float*)d_in[8];
    float* out = (float*)d_out;
    u16* ws = (u16*)d_ws;

    u16* WqkvT = ws;                    // 4096x2048 = 8388608
    u16* WoT = WqkvT + 8388608;         // 4194304
    u16* Xb = WoT + 4194304;            // 8388608 (dead after QKV GEMM)
    u16* QKVb = Xb + 8388608;           // 4096x4096 = 16777216
    u16* Vtb = QKVb + 16777216;         // 4194304
    u16* Ob = Xb;                       // alias
    // total 41,943,040 u16 = 83.9 MB

    prep_weights<<<dim3(64, 64, 5), dim3(32, 32), 0, stream>>>(Wq, Wk, Wv, Wo, X,
                                                               WqkvT, WoT, Xb);

    gemm256<u16><<<dim3(16, 16), 512, 0, stream>>>(Xb, WqkvT, QKVb, 4096, 4096, 2048);

    prep_qkv<<<28672, 256, 0, stream>>>(QKVb, Vtb, cosb, sinb, qw, kw);

    attn_kernel<<<1024, 256, 0, stream>>>(QKVb, Vtb, Ob);

    gemm128n<float><<<dim3(16, 16), 512, 0, stream>>>(Ob, WoT, out, 4096, 2048, 2048);
}

// Round 5
// 369.580 us; speedup vs baseline: 1.4828x; 1.4828x over previous
//
#include <hip/hip_runtime.h>
#include <hip/hip_bf16.h>

typedef unsigned short u16;
typedef unsigned int u32;
typedef unsigned long long u64;
typedef __attribute__((ext_vector_type(8))) short short8;
typedef __attribute__((ext_vector_type(4))) float floatx4;

#define AS1 __attribute__((address_space(1)))
#define AS3 __attribute__((address_space(3)))

// ---- bf16 <-> f32 helpers (raw bits, RNE) ----
__device__ __forceinline__ float bf2f(u16 u) {
    u32 x = ((u32)u) << 16;
    float f;
    __builtin_memcpy(&f, &x, 4);
    return f;
}
__device__ __forceinline__ u16 f2bf(float f) {
    u32 x;
    __builtin_memcpy(&x, &f, 4);
    u32 r = (x + 0x7fffu + ((x >> 16) & 1u)) >> 16;
    return (u16)r;
}
// packed 2xf32 -> 2xbf16 (v_cvt_pk_bf16_f32), returned as u32 (lo=first)
__device__ __forceinline__ u32 f2bf_pk(float a, float b) {
    __hip_bfloat162 h = __float22bfloat162_rn(float2{a, b});
    u32 r;
    __builtin_memcpy(&r, &h, 4);
    return r;
}

// ==========================================================================
// Merged prep: z<4 = weight transposes (f32 RxC -> bf16 CxR), z=4 = X cast.
// ==========================================================================
__global__ __launch_bounds__(1024) void prep_weights(const float* __restrict__ Wq,
                                                     const float* __restrict__ Wk,
                                                     const float* __restrict__ Wv,
                                                     const float* __restrict__ Wo,
                                                     const float* __restrict__ X,
                                                     u16* __restrict__ WqkvT,
                                                     u16* __restrict__ WoT,
                                                     u16* __restrict__ Xb) {
    const int z = blockIdx.z;
    const int tx = threadIdx.x, ty = threadIdx.y;
    if (z == 4) {  // convert X: 2048 active blocks x 4096 floats
        int idx = blockIdx.y * 64 + blockIdx.x;
        if (idx >= 2048) return;
        int tid = ty * 32 + tx;
        size_t i = (size_t)idx * 4096 + (size_t)tid * 4;
        float4 v = *(const float4*)(X + i);
        u16 o[4] = {f2bf(v.x), f2bf(v.y), f2bf(v.z), f2bf(v.w)};
        *(u64*)(Xb + i) = *(u64*)o;
        return;
    }
    const float* in;
    u16* out;
    int C;
    if (z == 0) { in = Wq; out = WqkvT; C = 2048; }
    else if (z == 1) { in = Wk; out = WqkvT + 2048 * 2048; C = 1024; }
    else if (z == 2) { in = Wv; out = WqkvT + 3072 * 2048; C = 1024; }
    else { in = Wo; out = WoT; C = 2048; }
    const int c0 = blockIdx.x * 32, r0 = blockIdx.y * 32;
    if (c0 >= C) return;
    __shared__ u16 t[32][33];
    t[ty][tx] = f2bf(in[(size_t)(r0 + ty) * C + c0 + tx]);
    __syncthreads();
    out[(size_t)(c0 + ty) * 2048 + r0 + tx] = t[tx][ty];
}

// ==========================================================================
// GEMM: C[M,N] = A[M,K] @ Bt[N,K]^T (bf16 in, fp32 acc, OUT_T out)
// 256x256 tile, BK=64, 512 thr (8 waves 2Mx4N), 8-phase-per-2-K-tiles
// schedule: counted vmcnt(6), raw s_barrier, XOR-swizzled LDS, setprio.
// ==========================================================================
template <typename OUT_T>
__global__ __launch_bounds__(512, 2) void gemm256(const u16* __restrict__ A,
                                                  const u16* __restrict__ Bt,
                                                  OUT_T* __restrict__ C,
                                                  int M, int N, int K) {
    (void)M;
    __shared__ __align__(16) u16 lds[2][2][2][128 * 64];  // [buf][A/B][half][r*64+c]
    const int tid = threadIdx.x;
    const int wave = tid >> 6, lane = tid & 63;
    const int lr = lane & 15, lq = lane >> 4;
    const int wm = wave >> 2, wn = wave & 3;
    const int m0 = blockIdx.y * 256, n0 = blockIdx.x * 256;

    const int srow = lane >> 3;                    // 0..7 within 8-row group
    const int schunk = ((lane & 7) ^ srow) << 3;   // source chunk (elems)
    const int slot = wave << 1;

    auto stage = [&](const u16* src, int rbase, int buf, int mat, int half, int k0) {
#pragma unroll
        for (int j = 0; j < 2; j++) {
            int r = rbase + half * 128 + (slot + j) * 8 + srow;
            __builtin_amdgcn_global_load_lds(
                (const AS1 void*)(src + (size_t)r * K + k0 + schunk),
                (AS3 void*)(&lds[buf][mat][half][(slot + j) * 512]), 16, 0, 0);
        }
    };

    floatx4 zf = {0.f, 0.f, 0.f, 0.f};
    floatx4 acc[8][4];
#pragma unroll
    for (int i = 0; i < 8; i++)
#pragma unroll
        for (int jn = 0; jn < 4; jn++) acc[i][jn] = zf;

    const int NT = K >> 6;

    stage(Bt, n0, 0, 1, 0, 0);
    stage(Bt, n0, 0, 1, 1, 0);
    stage(A, m0, 0, 0, 0, 0);
    stage(A, m0, 0, 0, 1, 0);
    if (NT > 1) {
        stage(Bt, n0, 1, 1, 0, 64);
        stage(Bt, n0, 1, 1, 1, 64);
        stage(A, m0, 1, 0, 0, 64);
        asm volatile("s_waitcnt vmcnt(6)" ::: "memory");
    } else {
        asm volatile("s_waitcnt vmcnt(0)" ::: "memory");
    }
    __builtin_amdgcn_s_barrier();

    for (int kt = 0; kt < NT; kt++) {
        const int b = kt & 1;
        const u16* Ab = &lds[b][0][wm][0];
        const u16* Bb = &lds[b][1][wn >> 1][0];
        const int brow = (wn & 1) * 64;
        const int sx = lr & 7;
        const int nk = (kt + 2) << 6;

        // ---- phase 0 ----
        short8 bf0[4], bf1[4], af[4];
#pragma unroll
        for (int jn = 0; jn < 4; jn++) {
            int rh = brow + jn * 16 + lr;
            bf0[jn] = *(const short8*)(Bb + rh * 64 + ((lq ^ sx) << 3));
            bf1[jn] = *(const short8*)(Bb + rh * 64 + (((4 + lq) ^ sx) << 3));
        }
#pragma unroll
        for (int i = 0; i < 4; i++)
            af[i] = *(const short8*)(Ab + (i * 16 + lr) * 64 + ((lq ^ sx) << 3));
        if (kt + 1 < NT) stage(A, m0, b ^ 1, 0, 1, (kt + 1) << 6);
        __builtin_amdgcn_s_barrier();
        asm volatile("s_waitcnt lgkmcnt(0)" ::: "memory");
        __builtin_amdgcn_sched_barrier(0);
        __builtin_amdgcn_s_setprio(1);
#pragma unroll
        for (int i = 0; i < 4; i++)
#pragma unroll
            for (int jn = 0; jn < 4; jn++)
                acc[i][jn] = __builtin_amdgcn_mfma_f32_16x16x32_bf16(af[i], bf0[jn], acc[i][jn], 0, 0, 0);
        __builtin_amdgcn_s_setprio(0);
        __builtin_amdgcn_s_barrier();

        // ---- phase 1 ----
        short8 ag[4];
#pragma unroll
        for (int i = 0; i < 4; i++)
            ag[i] = *(const short8*)(Ab + ((i + 4) * 16 + lr) * 64 + ((lq ^ sx) << 3));
        if (kt + 2 < NT) stage(Bt, n0, b, 1, 0, nk);
        __builtin_amdgcn_s_barrier();
        asm volatile("s_waitcnt lgkmcnt(0)" ::: "memory");
        __builtin_amdgcn_sched_barrier(0);
        __builtin_amdgcn_s_setprio(1);
#pragma unroll
        for (int i = 0; i < 4; i++)
#pragma unroll
            for (int jn = 0; jn < 4; jn++)
                acc[i + 4][jn] = __builtin_amdgcn_mfma_f32_16x16x32_bf16(ag[i], bf0[jn], acc[i + 4][jn], 0, 0, 0);
        __builtin_amdgcn_s_setprio(0);
        __builtin_amdgcn_s_barrier();

        // ---- phase 2 ----
        short8 c0[4], c1[4];
#pragma unroll
        for (int i = 0; i < 4; i++) {
            c0[i] = *(const short8*)(Ab + (i * 16 + lr) * 64 + (((4 + lq) ^ sx) << 3));
            c1[i] = *(const short8*)(Ab + ((i + 4) * 16 + lr) * 64 + (((4 + lq) ^ sx) << 3));
        }
        if (kt + 2 < NT) stage(Bt, n0, b, 1, 1, nk);
        __builtin_amdgcn_s_barrier();
        asm volatile("s_waitcnt lgkmcnt(0)" ::: "memory");
        __builtin_amdgcn_sched_barrier(0);
        __builtin_amdgcn_s_setprio(1);
#pragma unroll
        for (int i = 0; i < 4; i++)
#pragma unroll
            for (int jn = 0; jn < 4; jn++)
                acc[i][jn] = __builtin_amdgcn_mfma_f32_16x16x32_bf16(c0[i], bf1[jn], acc[i][jn], 0, 0, 0);
        __builtin_amdgcn_s_setprio(0);
        __builtin_amdgcn_s_barrier();

        // ---- phase 3 ----
        if (kt + 2 < NT) stage(A, m0, b, 0, 0, nk);
        __builtin_amdgcn_s_barrier();
        __builtin_amdgcn_s_setprio(1);
#pragma unroll
        for (int i = 0; i < 4; i++)
#pragma unroll
            for (int jn = 0; jn < 4; jn++)
                acc[i + 4][jn] = __builtin_amdgcn_mfma_f32_16x16x32_bf16(c1[i], bf1[jn], acc[i + 4][jn], 0, 0, 0);
        __builtin_amdgcn_s_setprio(0);
        if (kt + 2 < NT) asm volatile("s_waitcnt vmcnt(6)" ::: "memory");
        else asm volatile("s_waitcnt vmcnt(0)" ::: "memory");
        __builtin_amdgcn_s_barrier();
    }

#pragma unroll
    for (int i = 0; i < 8; i++)
#pragma unroll
        for (int jn = 0; jn < 4; jn++)
#pragma unroll
            for (int r = 0; r < 4; r++) {
                int row = m0 + wm * 128 + i * 16 + lq * 4 + r;
                int col = n0 + wn * 64 + jn * 16 + lr;
                if constexpr (sizeof(OUT_T) == 2)
                    C[(size_t)row * N + col] = f2bf(acc[i][jn][r]);
                else
                    C[(size_t)row * N + col] = acc[i][jn][r];
            }
}

// ==========================================================================
// GEMM: BM=256 x BN=128, BK=64, 512 thr = 8 waves (4M x 2N), 64x64/wave.
// Same 8-phase counted-vmcnt schedule; 3 stage-units/tile -> vmcnt(4).
// Grid (N/128, M/256) -> 256 blocks for the Wo GEMM (full GPU).
// ==========================================================================
template <typename OUT_T>
__global__ __launch_bounds__(512, 2) void gemm128n(const u16* __restrict__ A,
                                                   const u16* __restrict__ Bt,
                                                   OUT_T* __restrict__ C,
                                                   int M, int N, int K) {
    (void)M;
    __shared__ __align__(16) u16 Abuf[2][2][128 * 64];  // [buf][half][r*64+c]
    __shared__ __align__(16) u16 Bbuf[2][128 * 64];     // [buf][r*64+c]
    const int tid = threadIdx.x;
    const int wave = tid >> 6, lane = tid & 63;
    const int lr = lane & 15, lq = lane >> 4;
    const int wm = wave >> 1, wn = wave & 1;
    const int m0 = blockIdx.y * 256, n0 = blockIdx.x * 128;

    const int srow = lane >> 3;
    const int schunk = ((lane & 7) ^ srow) << 3;
    const int slot = wave << 1;

    auto stage = [&](const u16* src, int rowbase, u16* ldsbase, int k0) {
#pragma unroll
        for (int j = 0; j < 2; j++) {
            int r = rowbase + (slot + j) * 8 + srow;
            __builtin_amdgcn_global_load_lds(
                (const AS1 void*)(src + (size_t)r * K + k0 + schunk),
                (AS3 void*)(ldsbase + (slot + j) * 512), 16, 0, 0);
        }
    };

    floatx4 zf = {0.f, 0.f, 0.f, 0.f};
    floatx4 acc[4][4];
#pragma unroll
    for (int i = 0; i < 4; i++)
#pragma unroll
        for (int jn = 0; jn < 4; jn++) acc[i][jn] = zf;

    const int NT = K >> 6;

    // prologue: t0 = {Ah0, Ah1, B}; t1 = {Ah0, B} (Ah1(t1) comes in t0.ph0)
    stage(A, m0, &Abuf[0][0][0], 0);
    stage(A, m0 + 128, &Abuf[0][1][0], 0);
    stage(Bt, n0, &Bbuf[0][0], 0);
    if (NT > 1) {
        stage(A, m0, &Abuf[1][0][0], 64);
        stage(Bt, n0, &Bbuf[1][0], 64);
        asm volatile("s_waitcnt vmcnt(4)" ::: "memory");
    } else {
        asm volatile("s_waitcnt vmcnt(0)" ::: "memory");
    }
    __builtin_amdgcn_s_barrier();

    for (int kt = 0; kt < NT; kt++) {
        const int b = kt & 1;
        const u16* Ab = &Abuf[b][wm >> 1][0];
        const u16* Bb = &Bbuf[b][0];
        const int ar = (wm & 1) * 64;
        const int br = wn * 64;
        const int sx = lr & 7;
        const int nk = (kt + 2) << 6;

        // ---- phase 0: read bf0,bf1,af(kk0); stage Ah1(kt+1); mfma kk0 i0-1 ----
        short8 bf0[4], bf1[4], af[4];
#pragma unroll
        for (int jn = 0; jn < 4; jn++) {
            int rh = br + jn * 16 + lr;
            bf0[jn] = *(const short8*)(Bb + rh * 64 + ((lq ^ sx) << 3));
            bf1[jn] = *(const short8*)(Bb + rh * 64 + (((4 + lq) ^ sx) << 3));
        }
#pragma unroll
        for (int i = 0; i < 4; i++)
            af[i] = *(const short8*)(Ab + (ar + i * 16 + lr) * 64 + ((lq ^ sx) << 3));
        if (kt + 1 < NT) stage(A, m0 + 128, &Abuf[b ^ 1][1][0], (kt + 1) << 6);
        __builtin_amdgcn_s_barrier();
        asm volatile("s_waitcnt lgkmcnt(0)" ::: "memory");
        __builtin_amdgcn_sched_barrier(0);
        __builtin_amdgcn_s_setprio(1);
#pragma unroll
        for (int i = 0; i < 2; i++)
#pragma unroll
            for (int jn = 0; jn < 4; jn++)
                acc[i][jn] = __builtin_amdgcn_mfma_f32_16x16x32_bf16(af[i], bf0[jn], acc[i][jn], 0, 0, 0);
        __builtin_amdgcn_s_setprio(0);
        __builtin_amdgcn_s_barrier();

        // ---- phase 1: stage B(kt+2); mfma kk0 i2-3 ----
        if (kt + 2 < NT) stage(Bt, n0, &Bbuf[b][0], nk);
        __builtin_amdgcn_s_barrier();
        __builtin_amdgcn_s_setprio(1);
#pragma unroll
        for (int i = 2; i < 4; i++)
#pragma unroll
            for (int jn = 0; jn < 4; jn++)
                acc[i][jn] = __builtin_amdgcn_mfma_f32_16x16x32_bf16(af[i], bf0[jn], acc[i][jn], 0, 0, 0);
        __builtin_amdgcn_s_setprio(0);
        __builtin_amdgcn_s_barrier();

        // ---- phase 2: read ag(kk1); mfma kk1 i0-1 ----
        short8 ag[4];
#pragma unroll
        for (int i = 0; i < 4; i++)
            ag[i] = *(const short8*)(Ab + (ar + i * 16 + lr) * 64 + (((4 + lq) ^ sx) << 3));
        __builtin_amdgcn_s_barrier();
        asm volatile("s_waitcnt lgkmcnt(0)" ::: "memory");
        __builtin_amdgcn_sched_barrier(0);
        __builtin_amdgcn_s_setprio(1);
#pragma unroll
        for (int i = 0; i < 2; i++)
#pragma unroll
            for (int jn = 0; jn < 4; jn++)
                acc[i][jn] = __builtin_amdgcn_mfma_f32_16x16x32_bf16(ag[i], bf1[jn], acc[i][jn], 0, 0, 0);
        __builtin_amdgcn_s_setprio(0);
        __builtin_amdgcn_s_barrier();

        // ---- phase 3: stage Ah0(kt+2); mfma kk1 i2-3; counted vmcnt ----
        if (kt + 2 < NT) stage(A, m0, &Abuf[b][0][0], nk);
        __builtin_amdgcn_s_barrier();
        __builtin_amdgcn_s_setprio(1);
#pragma unroll
        for (int i = 2; i < 4; i++)
#pragma unroll
            for (int jn = 0; jn < 4; jn++)
                acc[i][jn] = __builtin_amdgcn_mfma_f32_16x16x32_bf16(ag[i], bf1[jn], acc[i][jn], 0, 0, 0);
        __builtin_amdgcn_s_setprio(0);
        if (kt + 2 < NT) asm volatile("s_waitcnt vmcnt(4)" ::: "memory");
        else asm volatile("s_waitcnt vmcnt(0)" ::: "memory");
        __builtin_amdgcn_s_barrier();
    }

#pragma unroll
    for (int i = 0; i < 4; i++)
#pragma unroll
        for (int jn = 0; jn < 4; jn++)
#pragma unroll
            for (int r = 0; r < 4; r++) {
                int row = m0 + wm * 64 + i * 16 + lq * 4 + r;
                int col = n0 + wn * 64 + jn * 16 + lr;
                if constexpr (sizeof(OUT_T) == 2)
                    C[(size_t)row * N + col] = f2bf(acc[i][jn][r]);
                else
                    C[(size_t)row * N + col] = acc[i][jn][r];
            }
}

// ==========================================================================
// Merged post-QKV prep: blocks <24576 do RMS-norm+RoPE on Q/K (in place);
// blocks >=24576 transpose V into Vt (b,kv,d,s). 256 threads each.
// ==========================================================================
__global__ __launch_bounds__(256) void prep_qkv(u16* __restrict__ QKV,
                                                u16* __restrict__ Vt,
                                                const float* __restrict__ cosb,
                                                const float* __restrict__ sinb,
                                                const float* __restrict__ qw,
                                                const float* __restrict__ kw) {
    const int bx = blockIdx.x;
    const int tid = threadIdx.x;
    if (bx >= 24576) {  // V transpose: 4096 blocks
        const int idx = bx - 24576;
        const int s0 = (idx & 63) * 32;
        const int d0 = ((idx >> 6) & 3) * 32;
        const int zz = idx >> 8;
        const int b = zz >> 3, kv = zz & 7;
        __shared__ u16 t[32][33];
        const int tx = tid & 31, ty0 = tid >> 5;  // 32 x 8
#pragma unroll
        for (int p = 0; p < 4; p++) {
            int r = ty0 + p * 8;
            t[r][tx] = QKV[(size_t)(b * 2048 + s0 + r) * 4096 + 3072 + kv * 128 + d0 + tx];
        }
        __syncthreads();
#pragma unroll
        for (int p = 0; p < 4; p++) {
            int r = ty0 + p * 8;
            Vt[(size_t)((b * 8 + kv) * 128 + d0 + r) * 2048 + s0 + tx] = t[tx][r];
        }
        return;
    }
    const int wave = tid >> 6, lane = tid & 63;
    const int t = bx * 4 + wave;  // 0..98303
    u16* ptr;
    const float* w;
    float scale;
    int bs;
    if (t < 65536) {
        bs = t >> 4;
        ptr = QKV + (size_t)bs * 4096 + (t & 15) * 128;
        w = qw;
        scale = 0.08838834764831845f * 1.4426950408889634f;  // D^-0.5 * log2(e)
    } else {
        int t2 = t - 65536;
        bs = t2 >> 3;
        ptr = QKV + (size_t)bs * 4096 + 2048 + (t2 & 7) * 128;
        w = kw;
        scale = 1.0f;
    }
    const int d = lane * 2;
    u32 xv = *(const u32*)(ptr + d);
    float x0 = bf2f((u16)(xv & 0xffff)), x1 = bf2f((u16)(xv >> 16));
    float ss = x0 * x0 + x1 * x1;
#pragma unroll
    for (int off = 1; off < 64; off <<= 1) ss += __shfl_xor(ss, off);
    float rn = rsqrtf(ss * (1.0f / 128.0f) + 1e-6f);
    float2 wv = *(const float2*)(w + d);
    float y0 = x0 * rn * wv.x;
    float y1 = x1 * rn * wv.y;
    float p0 = __shfl_xor(y0, 32);
    float p1 = __shfl_xor(y1, 32);
    float sgn = (lane < 32) ? -1.0f : 1.0f;
    float2 cv = *(const float2*)(cosb + (size_t)bs * 128 + d);
    float2 sv = *(const float2*)(sinb + (size_t)bs * 128 + d);
    float o0 = (y0 * cv.x + sgn * p0 * sv.x) * scale;
    float o1 = (y1 * cv.y + sgn * p1 * sv.y) * scale;
    *(u32*)(ptr + d) = (u32)f2bf(o0) | ((u32)f2bf(o1) << 16);
}

// ==========================================================================
// Causal GQA flash attention, transposed-score formulation.
// QBLK=64 (4 waves, 256 thr), KVBLK=64.
// LDS 48KB: K double-buffered (32KB, prefetched 1 tile ahead) + V
// SINGLE-buffered (16KB, staged at iteration top, consumed after a
// mid-iteration barrier -> HBM/L2 latency hides under QK^T+softmax).
// 3 blocks/CU = 12 waves/CU + 256-block backfill queue.
// LPT dispatch: qt = 31 - id/32 (longest blocks first; short qt=0 tail).
// T5 setprio, T13 defer-max, per-lane partial l.
// ==========================================================================
__global__ __launch_bounds__(256, 3) void attn_kernel(const u16* __restrict__ QKV,
                                                      const u16* __restrict__ Vt,
                                                      u16* __restrict__ O) {
    __shared__ __align__(16) u16 Ks[2][64 * 128];   // [key][d] swizzled, 32KB
    __shared__ __align__(16) u16 Vs[128 * 64];      // [d][key] swizzled, 16KB
    const int tid = threadIdx.x;
    const int wave = tid >> 6, lane = tid & 63;
    const int lr = lane & 15, lq = lane >> 4;

    // LPT decode: rank 0 = longest (qt=31)
    const int id = blockIdx.x;        // 0..1023
    const int qt = 31 - (id >> 5);
    const int j = id & 31;
    const int h = j & 15;
    const int b = j >> 4;

    const int kv = h >> 1;
    const int q0 = qt * 64;
    const int wq = wave * 16;

    // async stage of one 64-key K tile into buffer `buf` (4 instrs/wave)
    auto stageK = [&](int buf, int k0s) {
#pragma unroll
        for (int jj = 0; jj < 4; jj++) {   // Ks: 64 rows x 256 B
            int r = wave * 16 + jj * 4 + (lane >> 4);
            int ch = (lane & 15) ^ (r & 15);   // inverse-swizzled source chunk
            __builtin_amdgcn_global_load_lds(
                (const AS1 void*)(QKV + (size_t)(b * 2048 + k0s + r) * 4096 + 2048 + kv * 128 + ch * 8),
                (AS3 void*)(&Ks[buf][(wave * 16 + jj * 4) * 128]), 16, 0, 0);
        }
    };
    // async stage of the V tile (single buffer; consumed after barrier #2)
    auto stageV = [&](int k0s) {
#pragma unroll
        for (int jj = 0; jj < 4; jj++) {   // Vs: 128 rows x 128 B
            int r = wave * 32 + jj * 8 + (lane >> 3);
            int ch = (lane & 7) ^ (r & 7);
            __builtin_amdgcn_global_load_lds(
                (const AS1 void*)(Vt + (size_t)((b * 8 + kv) * 128 + r) * 2048 + k0s + ch * 8),
                (AS3 void*)(&Vs[(wave * 32 + jj * 8) * 64]), 16, 0, 0);
        }
    };

    // Q fragments in registers (B-operand: n=qrow on lr, k=d on lq*8+j)
    short8 qf[4];
#pragma unroll
    for (int t = 0; t < 4; t++)
        qf[t] = *(const short8*)(QKV + (size_t)(b * 2048 + q0 + wq + lr) * 4096 + h * 128 + t * 32 + lq * 8);

    floatx4 zf = {0.f, 0.f, 0.f, 0.f};
    floatx4 oacc[8];
#pragma unroll
    for (int jn = 0; jn < 8; jn++) oacc[jn] = zf;
    float mstate = -1e30f;
    float lstate = 0.f;   // per-lane partial; cross-quad reduce in epilogue

    const int nIter = qt + 1;

    stageK(0, 0);

    for (int kt = 0; kt < nIter; kt++) {
        const int k0 = kt * 64;
        const int cur = kt & 1;
        // barrier #1: K(kt) committed (staged last iter); Vs free (PV(kt-1)
        // finished before this barrier); Ks[cur^1] free for restage.
        __syncthreads();
        stageV(k0);
        if (kt + 1 < nIter) stageK(cur ^ 1, k0 + 64);

        const bool active = (k0 <= q0 + wq + 15);
        u64 pb[4];
        if (active) {
            const u16* KsC = &Ks[cur][0];
            floatx4 sacc[4];
#pragma unroll
            for (int jm = 0; jm < 4; jm++) sacc[jm] = zf;
            __builtin_amdgcn_s_setprio(1);
#pragma unroll
            for (int t = 0; t < 4; t++) {
                short8 a[4];
#pragma unroll
                for (int jm = 0; jm < 4; jm++)
                    a[jm] = *(const short8*)(KsC + (jm * 16 + lr) * 128 + (((t * 4 + lq) ^ lr) << 3));
#pragma unroll
                for (int jm = 0; jm < 4; jm++)
                    sacc[jm] = __builtin_amdgcn_mfma_f32_16x16x32_bf16(a[jm], qf[t], sacc[jm], 0, 0, 0);
            }
            __builtin_amdgcn_s_setprio(0);

            if (k0 + 63 > q0 + wq) {
#pragma unroll
                for (int jm = 0; jm < 4; jm++) {
                    int diff = (q0 + wq + lr) - (k0 + jm * 16 + lq * 4);
#pragma unroll
                    for (int r = 0; r < 4; r++)
                        if (r > diff) sacc[jm][r] = -1e30f;
                }
            }

            // per-qrow max (tree within jm, then cross-quad)
            float mx = -1e30f;
#pragma unroll
            for (int jm = 0; jm < 4; jm++) {
                float a0 = fmaxf(sacc[jm][0], sacc[jm][1]);
                float a1 = fmaxf(sacc[jm][2], sacc[jm][3]);
                mx = fmaxf(mx, fmaxf(a0, a1));
            }
            mx = fmaxf(mx, __shfl_xor(mx, 16));
            mx = fmaxf(mx, __shfl_xor(mx, 32));

            // T13 defer-max: skip rescale when all rows grew <= 8 (log2 dom)
            bool defer = __all(mx - mstate <= 8.0f);
            float mnew = defer ? mstate : fmaxf(mstate, mx);

            float rs = 0.f;
#pragma unroll
            for (int jm = 0; jm < 4; jm++)
#pragma unroll
                for (int r = 0; r < 4; r++) {
                    float p = exp2f(sacc[jm][r] - mnew);
                    sacc[jm][r] = p;
                    rs += p;
                }

            if (!defer) {
                float alpha = exp2f(mstate - mnew);
                mstate = mnew;
                lstate *= alpha;
                float ao[4];
#pragma unroll
                for (int r = 0; r < 4; r++) ao[r] = __shfl(alpha, lq * 4 + r);
#pragma unroll
                for (int jn = 0; jn < 8; jn++)
#pragma unroll
                    for (int r = 0; r < 4; r++) oacc[jn][r] *= ao[r];
            }
            lstate += rs;

#pragma unroll
            for (int jm = 0; jm < 4; jm++) {
                u32 lo = f2bf_pk(sacc[jm][0], sacc[jm][1]);
                u32 hi = f2bf_pk(sacc[jm][2], sacc[jm][3]);
                pb[jm] = (u64)lo | ((u64)hi << 32);
            }
        }

        // barrier #2: V(kt) committed (own + other waves' DMA drained by the
        // implicit vmcnt(0); softmax phase hid the load latency).
        __syncthreads();

        if (active) {
            // O += P @ V, permuted k-order; A-frag straight from registers,
            // B-frag = V at the same permuted keys (two 8B LDS reads each).
            __builtin_amdgcn_s_setprio(1);
#pragma unroll
            for (int t = 0; t < 2; t++) {
                union { short8 v; u64 q[2]; } pa;
                pa.q[0] = pb[2 * t];
                pa.q[1] = pb[2 * t + 1];
#pragma unroll
                for (int jn = 0; jn < 8; jn++) {
                    const u16* vrow = Vs + (jn * 16 + lr) * 64 + (lq & 1) * 4;
                    union { short8 v; u64 q[2]; } vb;
                    vb.q[0] = *(const u64*)(vrow + (((t * 4 + (lq >> 1)) ^ (lr & 7)) << 3));
                    vb.q[1] = *(const u64*)(vrow + (((t * 4 + 2 + (lq >> 1)) ^ (lr & 7)) << 3));
                    oacc[jn] = __builtin_amdgcn_mfma_f32_16x16x32_bf16(pa.v, vb.v, oacc[jn], 0, 0, 0);
                }
            }
            __builtin_amdgcn_s_setprio(0);
        }
    }

    // epilogue: finish l reduce, then O / l
    lstate += __shfl_xor(lstate, 16);
    lstate += __shfl_xor(lstate, 32);
    float lo[4];
#pragma unroll
    for (int r = 0; r < 4; r++) lo[r] = __shfl(lstate, lq * 4 + r);
#pragma unroll
    for (int jn = 0; jn < 8; jn++)
#pragma unroll
        for (int r = 0; r < 4; r++) {
            int row = q0 + wq + lq * 4 + r;
            O[(size_t)(b * 2048 + row) * 2048 + h * 128 + jn * 16 + lr] =
                f2bf(oacc[jn][r] / lo[r]);
        }
}

// ==========================================================================
extern "C" void kernel_launch(void* const* d_in, const int* in_sizes, int n_in,
                              void* d_out, int out_size, void* d_ws, size_t ws_size,
                              hipStream_t stream) {
    const float* X = (const float*)d_in[0];
    const float* cosb = (const float*)d_in[1];
    const float* sinb = (const float*)d_in[2];
    const float* Wq = (const float*)d_in[3];
    const float* Wk = (const float*)d_in[4];
    const float* Wv = (const float*)d_in[5];
    const float* Wo = (const float*)d_in[6];
    const float* qw = (const float*)d_in[7];
    const float* kw = (const float*)d_in[8];
    float* out = (float*)d_out;
    u16* ws = (u16*)d_ws;

    u16* WqkvT = ws;                    // 4096x2048 = 8388608
    u16* WoT = WqkvT + 8388608;         // 4194304
    u16* Xb = WoT + 4194304;            // 8388608 (dead after QKV GEMM)
    u16* QKVb = Xb + 8388608;           // 4096x4096 = 16777216
    u16* Vtb = QKVb + 16777216;         // 4194304
    u16* Ob = Xb;                       // alias
    // total 41,943,040 u16 = 83.9 MB

    prep_weights<<<dim3(64, 64, 5), dim3(32, 32), 0, stream>>>(Wq, Wk, Wv, Wo, X,
                                                               WqkvT, WoT, Xb);

    gemm256<u16><<<dim3(16, 16), 512, 0, stream>>>(Xb, WqkvT, QKVb, 4096, 4096, 2048);

    prep_qkv<<<28672, 256, 0, stream>>>(QKVb, Vtb, cosb, sinb, qw, kw);

    attn_kernel<<<1024, 256, 0, stream>>>(QKVb, Vtb, Ob);

    gemm128n<float><<<dim3(16, 16), 512, 0, stream>>>(Ob, WoT, out, 4096, 2048, 2048);
}

// Round 6
// 363.177 us; speedup vs baseline: 1.5089x; 1.0176x over previous
//
#include <hip/hip_runtime.h>
#include <hip/hip_bf16.h>

typedef unsigned short u16;
typedef unsigned int u32;
typedef unsigned long long u64;
typedef __attribute__((ext_vector_type(8))) short short8;
typedef __attribute__((ext_vector_type(4))) float floatx4;

#define AS1 __attribute__((address_space(1)))
#define AS3 __attribute__((address_space(3)))

// ---- bf16 <-> f32 helpers (raw bits, RNE) ----
__device__ __forceinline__ float bf2f(u16 u) {
    u32 x = ((u32)u) << 16;
    float f;
    __builtin_memcpy(&f, &x, 4);
    return f;
}
__device__ __forceinline__ u16 f2bf(float f) {
    u32 x;
    __builtin_memcpy(&x, &f, 4);
    u32 r = (x + 0x7fffu + ((x >> 16) & 1u)) >> 16;
    return (u16)r;
}
// packed 2xf32 -> 2xbf16 (v_cvt_pk_bf16_f32), returned as u32 (lo=first)
__device__ __forceinline__ u32 f2bf_pk(float a, float b) {
    __hip_bfloat162 h = __float22bfloat162_rn(float2{a, b});
    u32 r;
    __builtin_memcpy(&r, &h, 4);
    return r;
}

// ==========================================================================
// Merged prep: z<4 = weight transposes (f32 RxC -> bf16 CxR), z=4 = X cast.
// ==========================================================================
__global__ __launch_bounds__(1024) void prep_weights(const float* __restrict__ Wq,
                                                     const float* __restrict__ Wk,
                                                     const float* __restrict__ Wv,
                                                     const float* __restrict__ Wo,
                                                     const float* __restrict__ X,
                                                     u16* __restrict__ WqkvT,
                                                     u16* __restrict__ WoT,
                                                     u16* __restrict__ Xb) {
    const int z = blockIdx.z;
    const int tx = threadIdx.x, ty = threadIdx.y;
    if (z == 4) {  // convert X: 2048 active blocks x 4096 floats
        int idx = blockIdx.y * 64 + blockIdx.x;
        if (idx >= 2048) return;
        int tid = ty * 32 + tx;
        size_t i = (size_t)idx * 4096 + (size_t)tid * 4;
        float4 v = *(const float4*)(X + i);
        u16 o[4] = {f2bf(v.x), f2bf(v.y), f2bf(v.z), f2bf(v.w)};
        *(u64*)(Xb + i) = *(u64*)o;
        return;
    }
    const float* in;
    u16* out;
    int C;
    if (z == 0) { in = Wq; out = WqkvT; C = 2048; }
    else if (z == 1) { in = Wk; out = WqkvT + 2048 * 2048; C = 1024; }
    else if (z == 2) { in = Wv; out = WqkvT + 3072 * 2048; C = 1024; }
    else { in = Wo; out = WoT; C = 2048; }
    const int c0 = blockIdx.x * 32, r0 = blockIdx.y * 32;
    if (c0 >= C) return;
    __shared__ u16 t[32][33];
    t[ty][tx] = f2bf(in[(size_t)(r0 + ty) * C + c0 + tx]);
    __syncthreads();
    out[(size_t)(c0 + ty) * 2048 + r0 + tx] = t[tx][ty];
}

// ==========================================================================
// GEMM: C[M,N] = A[M,K] @ Bt[N,K]^T (bf16 in, fp32 acc, OUT_T out)
// 256x256 tile, BK=64, 512 thr (8 waves 2Mx4N), 8-phase-per-2-K-tiles
// schedule: counted vmcnt(6), raw s_barrier, XOR-swizzled LDS, setprio.
// ==========================================================================
template <typename OUT_T>
__global__ __launch_bounds__(512, 2) void gemm256(const u16* __restrict__ A,
                                                  const u16* __restrict__ Bt,
                                                  OUT_T* __restrict__ C,
                                                  int M, int N, int K) {
    (void)M;
    __shared__ __align__(16) u16 lds[2][2][2][128 * 64];  // [buf][A/B][half][r*64+c]
    const int tid = threadIdx.x;
    const int wave = tid >> 6, lane = tid & 63;
    const int lr = lane & 15, lq = lane >> 4;
    const int wm = wave >> 2, wn = wave & 3;
    const int m0 = blockIdx.y * 256, n0 = blockIdx.x * 256;

    const int srow = lane >> 3;                    // 0..7 within 8-row group
    const int schunk = ((lane & 7) ^ srow) << 3;   // source chunk (elems)
    const int slot = wave << 1;

    auto stage = [&](const u16* src, int rbase, int buf, int mat, int half, int k0) {
#pragma unroll
        for (int j = 0; j < 2; j++) {
            int r = rbase + half * 128 + (slot + j) * 8 + srow;
            __builtin_amdgcn_global_load_lds(
                (const AS1 void*)(src + (size_t)r * K + k0 + schunk),
                (AS3 void*)(&lds[buf][mat][half][(slot + j) * 512]), 16, 0, 0);
        }
    };

    floatx4 zf = {0.f, 0.f, 0.f, 0.f};
    floatx4 acc[8][4];
#pragma unroll
    for (int i = 0; i < 8; i++)
#pragma unroll
        for (int jn = 0; jn < 4; jn++) acc[i][jn] = zf;

    const int NT = K >> 6;

    stage(Bt, n0, 0, 1, 0, 0);
    stage(Bt, n0, 0, 1, 1, 0);
    stage(A, m0, 0, 0, 0, 0);
    stage(A, m0, 0, 0, 1, 0);
    if (NT > 1) {
        stage(Bt, n0, 1, 1, 0, 64);
        stage(Bt, n0, 1, 1, 1, 64);
        stage(A, m0, 1, 0, 0, 64);
        asm volatile("s_waitcnt vmcnt(6)" ::: "memory");
    } else {
        asm volatile("s_waitcnt vmcnt(0)" ::: "memory");
    }
    __builtin_amdgcn_s_barrier();

    for (int kt = 0; kt < NT; kt++) {
        const int b = kt & 1;
        const u16* Ab = &lds[b][0][wm][0];
        const u16* Bb = &lds[b][1][wn >> 1][0];
        const int brow = (wn & 1) * 64;
        const int sx = lr & 7;
        const int nk = (kt + 2) << 6;

        // ---- phase 0 ----
        short8 bf0[4], bf1[4], af[4];
#pragma unroll
        for (int jn = 0; jn < 4; jn++) {
            int rh = brow + jn * 16 + lr;
            bf0[jn] = *(const short8*)(Bb + rh * 64 + ((lq ^ sx) << 3));
            bf1[jn] = *(const short8*)(Bb + rh * 64 + (((4 + lq) ^ sx) << 3));
        }
#pragma unroll
        for (int i = 0; i < 4; i++)
            af[i] = *(const short8*)(Ab + (i * 16 + lr) * 64 + ((lq ^ sx) << 3));
        if (kt + 1 < NT) stage(A, m0, b ^ 1, 0, 1, (kt + 1) << 6);
        __builtin_amdgcn_s_barrier();
        asm volatile("s_waitcnt lgkmcnt(0)" ::: "memory");
        __builtin_amdgcn_sched_barrier(0);
        __builtin_amdgcn_s_setprio(1);
#pragma unroll
        for (int i = 0; i < 4; i++)
#pragma unroll
            for (int jn = 0; jn < 4; jn++)
                acc[i][jn] = __builtin_amdgcn_mfma_f32_16x16x32_bf16(af[i], bf0[jn], acc[i][jn], 0, 0, 0);
        __builtin_amdgcn_s_setprio(0);
        __builtin_amdgcn_s_barrier();

        // ---- phase 1 ----
        short8 ag[4];
#pragma unroll
        for (int i = 0; i < 4; i++)
            ag[i] = *(const short8*)(Ab + ((i + 4) * 16 + lr) * 64 + ((lq ^ sx) << 3));
        if (kt + 2 < NT) stage(Bt, n0, b, 1, 0, nk);
        __builtin_amdgcn_s_barrier();
        asm volatile("s_waitcnt lgkmcnt(0)" ::: "memory");
        __builtin_amdgcn_sched_barrier(0);
        __builtin_amdgcn_s_setprio(1);
#pragma unroll
        for (int i = 0; i < 4; i++)
#pragma unroll
            for (int jn = 0; jn < 4; jn++)
                acc[i + 4][jn] = __builtin_amdgcn_mfma_f32_16x16x32_bf16(ag[i], bf0[jn], acc[i + 4][jn], 0, 0, 0);
        __builtin_amdgcn_s_setprio(0);
        __builtin_amdgcn_s_barrier();

        // ---- phase 2 ----
        short8 c0[4], c1[4];
#pragma unroll
        for (int i = 0; i < 4; i++) {
            c0[i] = *(const short8*)(Ab + (i * 16 + lr) * 64 + (((4 + lq) ^ sx) << 3));
            c1[i] = *(const short8*)(Ab + ((i + 4) * 16 + lr) * 64 + (((4 + lq) ^ sx) << 3));
        }
        if (kt + 2 < NT) stage(Bt, n0, b, 1, 1, nk);
        __builtin_amdgcn_s_barrier();
        asm volatile("s_waitcnt lgkmcnt(0)" ::: "memory");
        __builtin_amdgcn_sched_barrier(0);
        __builtin_amdgcn_s_setprio(1);
#pragma unroll
        for (int i = 0; i < 4; i++)
#pragma unroll
            for (int jn = 0; jn < 4; jn++)
                acc[i][jn] = __builtin_amdgcn_mfma_f32_16x16x32_bf16(c0[i], bf1[jn], acc[i][jn], 0, 0, 0);
        __builtin_amdgcn_s_setprio(0);
        __builtin_amdgcn_s_barrier();

        // ---- phase 3 ----
        if (kt + 2 < NT) stage(A, m0, b, 0, 0, nk);
        __builtin_amdgcn_s_barrier();
        __builtin_amdgcn_s_setprio(1);
#pragma unroll
        for (int i = 0; i < 4; i++)
#pragma unroll
            for (int jn = 0; jn < 4; jn++)
                acc[i + 4][jn] = __builtin_amdgcn_mfma_f32_16x16x32_bf16(c1[i], bf1[jn], acc[i + 4][jn], 0, 0, 0);
        __builtin_amdgcn_s_setprio(0);
        if (kt + 2 < NT) asm volatile("s_waitcnt vmcnt(6)" ::: "memory");
        else asm volatile("s_waitcnt vmcnt(0)" ::: "memory");
        __builtin_amdgcn_s_barrier();
    }

#pragma unroll
    for (int i = 0; i < 8; i++)
#pragma unroll
        for (int jn = 0; jn < 4; jn++)
#pragma unroll
            for (int r = 0; r < 4; r++) {
                int row = m0 + wm * 128 + i * 16 + lq * 4 + r;
                int col = n0 + wn * 64 + jn * 16 + lr;
                if constexpr (sizeof(OUT_T) == 2)
                    C[(size_t)row * N + col] = f2bf(acc[i][jn][r]);
                else
                    C[(size_t)row * N + col] = acc[i][jn][r];
            }
}

// ==========================================================================
// GEMM: BM=256 x BN=128, BK=64, 512 thr = 8 waves (4M x 2N), 64x64/wave.
// Same 8-phase counted-vmcnt schedule; 3 stage-units/tile -> vmcnt(4).
// Grid (N/128, M/256) -> 256 blocks for the Wo GEMM (full GPU).
// ==========================================================================
template <typename OUT_T>
__global__ __launch_bounds__(512, 2) void gemm128n(const u16* __restrict__ A,
                                                   const u16* __restrict__ Bt,
                                                   OUT_T* __restrict__ C,
                                                   int M, int N, int K) {
    (void)M;
    __shared__ __align__(16) u16 Abuf[2][2][128 * 64];  // [buf][half][r*64+c]
    __shared__ __align__(16) u16 Bbuf[2][128 * 64];     // [buf][r*64+c]
    const int tid = threadIdx.x;
    const int wave = tid >> 6, lane = tid & 63;
    const int lr = lane & 15, lq = lane >> 4;
    const int wm = wave >> 1, wn = wave & 1;
    const int m0 = blockIdx.y * 256, n0 = blockIdx.x * 128;

    const int srow = lane >> 3;
    const int schunk = ((lane & 7) ^ srow) << 3;
    const int slot = wave << 1;

    auto stage = [&](const u16* src, int rowbase, u16* ldsbase, int k0) {
#pragma unroll
        for (int j = 0; j < 2; j++) {
            int r = rowbase + (slot + j) * 8 + srow;
            __builtin_amdgcn_global_load_lds(
                (const AS1 void*)(src + (size_t)r * K + k0 + schunk),
                (AS3 void*)(ldsbase + (slot + j) * 512), 16, 0, 0);
        }
    };

    floatx4 zf = {0.f, 0.f, 0.f, 0.f};
    floatx4 acc[4][4];
#pragma unroll
    for (int i = 0; i < 4; i++)
#pragma unroll
        for (int jn = 0; jn < 4; jn++) acc[i][jn] = zf;

    const int NT = K >> 6;

    // prologue: t0 = {Ah0, Ah1, B}; t1 = {Ah0, B} (Ah1(t1) comes in t0.ph0)
    stage(A, m0, &Abuf[0][0][0], 0);
    stage(A, m0 + 128, &Abuf[0][1][0], 0);
    stage(Bt, n0, &Bbuf[0][0], 0);
    if (NT > 1) {
        stage(A, m0, &Abuf[1][0][0], 64);
        stage(Bt, n0, &Bbuf[1][0], 64);
        asm volatile("s_waitcnt vmcnt(4)" ::: "memory");
    } else {
        asm volatile("s_waitcnt vmcnt(0)" ::: "memory");
    }
    __builtin_amdgcn_s_barrier();

    for (int kt = 0; kt < NT; kt++) {
        const int b = kt & 1;
        const u16* Ab = &Abuf[b][wm >> 1][0];
        const u16* Bb = &Bbuf[b][0];
        const int ar = (wm & 1) * 64;
        const int br = wn * 64;
        const int sx = lr & 7;
        const int nk = (kt + 2) << 6;

        // ---- phase 0: read bf0,bf1,af(kk0); stage Ah1(kt+1); mfma kk0 i0-1 ----
        short8 bf0[4], bf1[4], af[4];
#pragma unroll
        for (int jn = 0; jn < 4; jn++) {
            int rh = br + jn * 16 + lr;
            bf0[jn] = *(const short8*)(Bb + rh * 64 + ((lq ^ sx) << 3));
            bf1[jn] = *(const short8*)(Bb + rh * 64 + (((4 + lq) ^ sx) << 3));
        }
#pragma unroll
        for (int i = 0; i < 4; i++)
            af[i] = *(const short8*)(Ab + (ar + i * 16 + lr) * 64 + ((lq ^ sx) << 3));
        if (kt + 1 < NT) stage(A, m0 + 128, &Abuf[b ^ 1][1][0], (kt + 1) << 6);
        __builtin_amdgcn_s_barrier();
        asm volatile("s_waitcnt lgkmcnt(0)" ::: "memory");
        __builtin_amdgcn_sched_barrier(0);
        __builtin_amdgcn_s_setprio(1);
#pragma unroll
        for (int i = 0; i < 2; i++)
#pragma unroll
            for (int jn = 0; jn < 4; jn++)
                acc[i][jn] = __builtin_amdgcn_mfma_f32_16x16x32_bf16(af[i], bf0[jn], acc[i][jn], 0, 0, 0);
        __builtin_amdgcn_s_setprio(0);
        __builtin_amdgcn_s_barrier();

        // ---- phase 1: stage B(kt+2); mfma kk0 i2-3 ----
        if (kt + 2 < NT) stage(Bt, n0, &Bbuf[b][0], nk);
        __builtin_amdgcn_s_barrier();
        __builtin_amdgcn_s_setprio(1);
#pragma unroll
        for (int i = 2; i < 4; i++)
#pragma unroll
            for (int jn = 0; jn < 4; jn++)
                acc[i][jn] = __builtin_amdgcn_mfma_f32_16x16x32_bf16(af[i], bf0[jn], acc[i][jn], 0, 0, 0);
        __builtin_amdgcn_s_setprio(0);
        __builtin_amdgcn_s_barrier();

        // ---- phase 2: read ag(kk1); mfma kk1 i0-1 ----
        short8 ag[4];
#pragma unroll
        for (int i = 0; i < 4; i++)
            ag[i] = *(const short8*)(Ab + (ar + i * 16 + lr) * 64 + (((4 + lq) ^ sx) << 3));
        __builtin_amdgcn_s_barrier();
        asm volatile("s_waitcnt lgkmcnt(0)" ::: "memory");
        __builtin_amdgcn_sched_barrier(0);
        __builtin_amdgcn_s_setprio(1);
#pragma unroll
        for (int i = 0; i < 2; i++)
#pragma unroll
            for (int jn = 0; jn < 4; jn++)
                acc[i][jn] = __builtin_amdgcn_mfma_f32_16x16x32_bf16(ag[i], bf1[jn], acc[i][jn], 0, 0, 0);
        __builtin_amdgcn_s_setprio(0);
        __builtin_amdgcn_s_barrier();

        // ---- phase 3: stage Ah0(kt+2); mfma kk1 i2-3; counted vmcnt ----
        if (kt + 2 < NT) stage(A, m0, &Abuf[b][0][0], nk);
        __builtin_amdgcn_s_barrier();
        __builtin_amdgcn_s_setprio(1);
#pragma unroll
        for (int i = 2; i < 4; i++)
#pragma unroll
            for (int jn = 0; jn < 4; jn++)
                acc[i][jn] = __builtin_amdgcn_mfma_f32_16x16x32_bf16(ag[i], bf1[jn], acc[i][jn], 0, 0, 0);
        __builtin_amdgcn_s_setprio(0);
        if (kt + 2 < NT) asm volatile("s_waitcnt vmcnt(4)" ::: "memory");
        else asm volatile("s_waitcnt vmcnt(0)" ::: "memory");
        __builtin_amdgcn_s_barrier();
    }

#pragma unroll
    for (int i = 0; i < 4; i++)
#pragma unroll
        for (int jn = 0; jn < 4; jn++)
#pragma unroll
            for (int r = 0; r < 4; r++) {
                int row = m0 + wm * 64 + i * 16 + lq * 4 + r;
                int col = n0 + wn * 64 + jn * 16 + lr;
                if constexpr (sizeof(OUT_T) == 2)
                    C[(size_t)row * N + col] = f2bf(acc[i][jn][r]);
                else
                    C[(size_t)row * N + col] = acc[i][jn][r];
            }
}

// ==========================================================================
// Merged post-QKV prep: blocks <24576 do RMS-norm+RoPE on Q/K (in place);
// blocks >=24576 transpose V into Vt (b,kv,d,s). 256 threads each.
// ==========================================================================
__global__ __launch_bounds__(256) void prep_qkv(u16* __restrict__ QKV,
                                                u16* __restrict__ Vt,
                                                const float* __restrict__ cosb,
                                                const float* __restrict__ sinb,
                                                const float* __restrict__ qw,
                                                const float* __restrict__ kw) {
    const int bx = blockIdx.x;
    const int tid = threadIdx.x;
    if (bx >= 24576) {  // V transpose: 4096 blocks
        const int idx = bx - 24576;
        const int s0 = (idx & 63) * 32;
        const int d0 = ((idx >> 6) & 3) * 32;
        const int zz = idx >> 8;
        const int b = zz >> 3, kv = zz & 7;
        __shared__ u16 t[32][33];
        const int tx = tid & 31, ty0 = tid >> 5;  // 32 x 8
#pragma unroll
        for (int p = 0; p < 4; p++) {
            int r = ty0 + p * 8;
            t[r][tx] = QKV[(size_t)(b * 2048 + s0 + r) * 4096 + 3072 + kv * 128 + d0 + tx];
        }
        __syncthreads();
#pragma unroll
        for (int p = 0; p < 4; p++) {
            int r = ty0 + p * 8;
            Vt[(size_t)((b * 8 + kv) * 128 + d0 + r) * 2048 + s0 + tx] = t[tx][r];
        }
        return;
    }
    const int wave = tid >> 6, lane = tid & 63;
    const int t = bx * 4 + wave;  // 0..98303
    u16* ptr;
    const float* w;
    float scale;
    int bs;
    if (t < 65536) {
        bs = t >> 4;
        ptr = QKV + (size_t)bs * 4096 + (t & 15) * 128;
        w = qw;
        scale = 0.08838834764831845f * 1.4426950408889634f;  // D^-0.5 * log2(e)
    } else {
        int t2 = t - 65536;
        bs = t2 >> 3;
        ptr = QKV + (size_t)bs * 4096 + 2048 + (t2 & 7) * 128;
        w = kw;
        scale = 1.0f;
    }
    const int d = lane * 2;
    u32 xv = *(const u32*)(ptr + d);
    float x0 = bf2f((u16)(xv & 0xffff)), x1 = bf2f((u16)(xv >> 16));
    float ss = x0 * x0 + x1 * x1;
#pragma unroll
    for (int off = 1; off < 64; off <<= 1) ss += __shfl_xor(ss, off);
    float rn = rsqrtf(ss * (1.0f / 128.0f) + 1e-6f);
    float2 wv = *(const float2*)(w + d);
    float y0 = x0 * rn * wv.x;
    float y1 = x1 * rn * wv.y;
    float p0 = __shfl_xor(y0, 32);
    float p1 = __shfl_xor(y1, 32);
    float sgn = (lane < 32) ? -1.0f : 1.0f;
    float2 cv = *(const float2*)(cosb + (size_t)bs * 128 + d);
    float2 sv = *(const float2*)(sinb + (size_t)bs * 128 + d);
    float o0 = (y0 * cv.x + sgn * p0 * sv.x) * scale;
    float o1 = (y1 * cv.y + sgn * p1 * sv.y) * scale;
    *(u32*)(ptr + d) = (u32)f2bf(o0) | ((u32)f2bf(o1) << 16);
}

// ==========================================================================
// Causal GQA flash attention, transposed-score formulation.
// QBLK=64 (4 waves, 256 thr), KVBLK=64.
// LDS 50KB: K double-buffered (32KB) + V single-buffered (16KB) + 16 rows
// of bf16 ones (2KB) appended to Vs so PV's jn=8 column accumulates
// l = sum(P) inside the MFMA (rescale-by-alpha applies automatically).
// Counted-vmcnt barriers (T4): pre-PV waits vmcnt(4) -> only V drained,
// K(kt+1) prefetch stays in flight across PV + next barrier. Top-of-tile
// vmcnt(0) is exact (only K(kt) outstanding there).
// 3 blocks/CU = 12 waves/CU + backfill; LPT dispatch (qt = 31 - id/32).
// T5 setprio, T13 defer-max.
// ==========================================================================
__global__ __launch_bounds__(256, 3) void attn_kernel(const u16* __restrict__ QKV,
                                                      const u16* __restrict__ Vt,
                                                      u16* __restrict__ O) {
    __shared__ __align__(16) u16 Ks[2][64 * 128];   // [key][d] swizzled, 32KB
    __shared__ __align__(16) u16 Vs[144 * 64];      // [d][key] swizzled + ones rows 128..143
    const int tid = threadIdx.x;
    const int wave = tid >> 6, lane = tid & 63;
    const int lr = lane & 15, lq = lane >> 4;

    // LPT decode: rank 0 = longest (qt=31)
    const int id = blockIdx.x;        // 0..1023
    const int qt = 31 - (id >> 5);
    const int j = id & 31;
    const int h = j & 15;
    const int b = j >> 4;

    const int kv = h >> 1;
    const int q0 = qt * 64;
    const int wq = wave * 16;

    // async stage of one 64-key K tile into buffer `buf` (4 instrs/wave)
    auto stageK = [&](int buf, int k0s) {
#pragma unroll
        for (int jj = 0; jj < 4; jj++) {   // Ks: 64 rows x 256 B
            int r = wave * 16 + jj * 4 + (lane >> 4);
            int ch = (lane & 15) ^ (r & 15);   // inverse-swizzled source chunk
            __builtin_amdgcn_global_load_lds(
                (const AS1 void*)(QKV + (size_t)(b * 2048 + k0s + r) * 4096 + 2048 + kv * 128 + ch * 8),
                (AS3 void*)(&Ks[buf][(wave * 16 + jj * 4) * 128]), 16, 0, 0);
        }
    };
    // async stage of the V tile (rows 0..127 only; ones rows untouched)
    auto stageV = [&](int k0s) {
#pragma unroll
        for (int jj = 0; jj < 4; jj++) {   // Vs: 128 rows x 128 B
            int r = wave * 32 + jj * 8 + (lane >> 3);
            int ch = (lane & 7) ^ (r & 7);
            __builtin_amdgcn_global_load_lds(
                (const AS1 void*)(Vt + (size_t)((b * 8 + kv) * 128 + r) * 2048 + k0s + ch * 8),
                (AS3 void*)(&Vs[(wave * 32 + jj * 8) * 64]), 16, 0, 0);
        }
    };

    // fill ones rows (128..143) once; any swizzled read sees 1.0
    *(u64*)(&Vs[128 * 64 + tid * 4]) = 0x3F803F803F803F80ULL;
    asm volatile("s_waitcnt lgkmcnt(0)" ::: "memory");

    // Q fragments in registers (B-operand: n=qrow on lr, k=d on lq*8+j)
    short8 qf[4];
#pragma unroll
    for (int t = 0; t < 4; t++)
        qf[t] = *(const short8*)(QKV + (size_t)(b * 2048 + q0 + wq + lr) * 4096 + h * 128 + t * 32 + lq * 8);

    floatx4 zf = {0.f, 0.f, 0.f, 0.f};
    floatx4 oacc[9];   // [8] = l column (ones rows of Vs)
#pragma unroll
    for (int jn = 0; jn < 9; jn++) oacc[jn] = zf;
    float mstate = -1e30f;

    const int nIter = qt + 1;

    stageK(0, 0);

    for (int kt = 0; kt < nIter; kt++) {
        const int k0 = kt * 64;
        const int cur = kt & 1;
        // barrier #1: own outstanding = K(kt) only -> vmcnt(0) is exact.
        // Vs free (PV(kt-1) done), Ks[cur^1] free (QK^T(kt-1) done).
        asm volatile("s_waitcnt vmcnt(0)" ::: "memory");
        __builtin_amdgcn_s_barrier();
        stageV(k0);
        if (kt + 1 < nIter) stageK(cur ^ 1, k0 + 64);

        const bool active = (k0 <= q0 + wq + 15);
        u64 pb[4];
        if (active) {
            const u16* KsC = &Ks[cur][0];
            floatx4 sacc[4];
#pragma unroll
            for (int jm = 0; jm < 4; jm++) sacc[jm] = zf;
            __builtin_amdgcn_s_setprio(1);
#pragma unroll
            for (int t = 0; t < 4; t++) {
                short8 a[4];
#pragma unroll
                for (int jm = 0; jm < 4; jm++)
                    a[jm] = *(const short8*)(KsC + (jm * 16 + lr) * 128 + (((t * 4 + lq) ^ lr) << 3));
#pragma unroll
                for (int jm = 0; jm < 4; jm++)
                    sacc[jm] = __builtin_amdgcn_mfma_f32_16x16x32_bf16(a[jm], qf[t], sacc[jm], 0, 0, 0);
            }
            __builtin_amdgcn_s_setprio(0);

            if (k0 + 63 > q0 + wq) {
#pragma unroll
                for (int jm = 0; jm < 4; jm++) {
                    int diff = (q0 + wq + lr) - (k0 + jm * 16 + lq * 4);
#pragma unroll
                    for (int r = 0; r < 4; r++)
                        if (r > diff) sacc[jm][r] = -1e30f;
                }
            }

            // per-qrow max (tree within jm, then cross-quad)
            float mx = -1e30f;
#pragma unroll
            for (int jm = 0; jm < 4; jm++) {
                float a0 = fmaxf(sacc[jm][0], sacc[jm][1]);
                float a1 = fmaxf(sacc[jm][2], sacc[jm][3]);
                mx = fmaxf(mx, fmaxf(a0, a1));
            }
            mx = fmaxf(mx, __shfl_xor(mx, 16));
            mx = fmaxf(mx, __shfl_xor(mx, 32));

            // T13 defer-max: skip rescale when all rows grew <= 8 (log2 dom)
            bool defer = __all(mx - mstate <= 8.0f);
            float mnew = defer ? mstate : fmaxf(mstate, mx);

#pragma unroll
            for (int jm = 0; jm < 4; jm++)
#pragma unroll
                for (int r = 0; r < 4; r++)
                    sacc[jm][r] = exp2f(sacc[jm][r] - mnew);

            if (!defer) {
                float alpha = exp2f(mstate - mnew);
                mstate = mnew;
                float ao[4];
#pragma unroll
                for (int r = 0; r < 4; r++) ao[r] = __shfl(alpha, lq * 4 + r);
#pragma unroll
                for (int jn = 0; jn < 9; jn++)   // includes l column
#pragma unroll
                    for (int r = 0; r < 4; r++) oacc[jn][r] *= ao[r];
            }

#pragma unroll
            for (int jm = 0; jm < 4; jm++) {
                u32 lo = f2bf_pk(sacc[jm][0], sacc[jm][1]);
                u32 hi = f2bf_pk(sacc[jm][2], sacc[jm][3]);
                pb[jm] = (u64)lo | ((u64)hi << 32);
            }
        }

        // barrier #2: wait ONLY the V loads (first 4 in own queue);
        // K(kt+1) (4 newer loads) stays in flight across PV + next barrier.
        if (kt + 1 < nIter) asm volatile("s_waitcnt vmcnt(4)" ::: "memory");
        else                asm volatile("s_waitcnt vmcnt(0)" ::: "memory");
        __builtin_amdgcn_s_barrier();

        if (active) {
            // O += P @ [V | 1]; jn=8 accumulates l per qrow inside MFMA.
            __builtin_amdgcn_s_setprio(1);
#pragma unroll
            for (int t = 0; t < 2; t++) {
                union { short8 v; u64 q[2]; } pa;
                pa.q[0] = pb[2 * t];
                pa.q[1] = pb[2 * t + 1];
#pragma unroll
                for (int jn = 0; jn < 9; jn++) {
                    const u16* vrow = Vs + (jn * 16 + lr) * 64 + (lq & 1) * 4;
                    union { short8 v; u64 q[2]; } vb;
                    vb.q[0] = *(const u64*)(vrow + (((t * 4 + (lq >> 1)) ^ (lr & 7)) << 3));
                    vb.q[1] = *(const u64*)(vrow + (((t * 4 + 2 + (lq >> 1)) ^ (lr & 7)) << 3));
                    oacc[jn] = __builtin_amdgcn_mfma_f32_16x16x32_bf16(pa.v, vb.v, oacc[jn], 0, 0, 0);
                }
            }
            __builtin_amdgcn_s_setprio(0);
        }
    }

    // epilogue: l already at the right lanes (oacc[8][r], qrow = lq*4+r)
#pragma unroll
    for (int jn = 0; jn < 8; jn++)
#pragma unroll
        for (int r = 0; r < 4; r++) {
            int row = q0 + wq + lq * 4 + r;
            O[(size_t)(b * 2048 + row) * 2048 + h * 128 + jn * 16 + lr] =
                f2bf(oacc[jn][r] / oacc[8][r]);
        }
}

// ==========================================================================
extern "C" void kernel_launch(void* const* d_in, const int* in_sizes, int n_in,
                              void* d_out, int out_size, void* d_ws, size_t ws_size,
                              hipStream_t stream) {
    const float* X = (const float*)d_in[0];
    const float* cosb = (const float*)d_in[1];
    const float* sinb = (const float*)d_in[2];
    const float* Wq = (const float*)d_in[3];
    const float* Wk = (const float*)d_in[4];
    const float* Wv = (const float*)d_in[5];
    const float* Wo = (const float*)d_in[6];
    const float* qw = (const float*)d_in[7];
    const float* kw = (const float*)d_in[8];
    float* out = (float*)d_out;
    u16* ws = (u16*)d_ws;

    u16* WqkvT = ws;                    // 4096x2048 = 8388608
    u16* WoT = WqkvT + 8388608;         // 4194304
    u16* Xb = WoT + 4194304;            // 8388608 (dead after QKV GEMM)
    u16* QKVb = Xb + 8388608;           // 4096x4096 = 16777216
    u16* Vtb = QKVb + 16777216;         // 4194304
    u16* Ob = Xb;                       // alias
    // total 41,943,040 u16 = 83.9 MB

    prep_weights<<<dim3(64, 64, 5), dim3(32, 32), 0, stream>>>(Wq, Wk, Wv, Wo, X,
                                                               WqkvT, WoT, Xb);

    gemm256<u16><<<dim3(16, 16), 512, 0, stream>>>(Xb, WqkvT, QKVb, 4096, 4096, 2048);

    prep_qkv<<<28672, 256, 0, stream>>>(QKVb, Vtb, cosb, sinb, qw, kw);

    attn_kernel<<<1024, 256, 0, stream>>>(QKVb, Vtb, Ob);

    gemm128n<float><<<dim3(16, 16), 512, 0, stream>>>(Ob, WoT, out, 4096, 2048, 2048);
}